// Round 14
// baseline (210.973 us; speedup 1.0000x reference)
//
#include <hip/hip_runtime.h>
#include <hip/hip_bf16.h>
#include <math.h>

#define B_      8
#define CIN     256
#define CMID    512
#define COUT    256
#define N_      2048
#define SCALE_  10.0f
#define EPS_THR 1e-3f
#define NORM_EPS_ 1e-12f

typedef __attribute__((ext_vector_type(8))) short short8;
typedef __attribute__((ext_vector_type(4))) float f32x4;

__device__ __forceinline__ ushort f2bf(float x) {
    union { float f; uint u; } v; v.f = x;
    uint r = v.u + 0x7FFF + ((v.u >> 16) & 1);
    return (ushort)(r >> 16);
}
__device__ __forceinline__ float bf2f(ushort h) {
    union { uint u; float f; } v; v.u = ((uint)h) << 16;
    return v.f;
}
__device__ __forceinline__ void gload_lds16(const void* g, void* l) {
    __builtin_amdgcn_global_load_lds((const __attribute__((address_space(1))) void*)g,
                                     (__attribute__((address_space(3))) void*)l, 16, 0, 0);
}

// ---------------- K0: weights fp32 -> bf16 ------------------------------------------
__global__ __launch_bounds__(256) void prep_w(const float* __restrict__ W1,
                                              const float* __restrict__ W2,
                                              ushort* __restrict__ W1b,
                                              ushort* __restrict__ W2b) {
    int idx = blockIdx.x * 256 + threadIdx.x;   // 0..131071
    W1b[idx] = f2bf(W1[idx]);
    W2b[idx] = f2bf(W2[idx]);
}

// ---------------- K1: conv1 fused with input transpose (R12 version) ----------------
#define ASTRIDE 40
__global__ __launch_bounds__(512) void conv1_fused(const float* __restrict__ q,
                                                   const float* __restrict__ k,
                                                   const ushort* __restrict__ W1b,
                                                   ushort* __restrict__ H) {
    __shared__ ushort As[64 * ASTRIDE];   // 5 KB, padded stride
    __shared__ ushort Bs[512 * 32];       // 32 KB
    int tid = threadIdx.x;
    int lane = tid & 63, wave = tid >> 6;
    int g = lane >> 4, cl = lane & 15;
    int bx = blockIdx.x;
    int half = bx >> 8;
    int u = bx & 255;
    int pb = u & 7, pj = u >> 3;          // pj in [0,32)
    size_t m0 = ((size_t)half * 256 + (size_t)pb * 32 + pj) * 64;
    const float* xsrc = (m0 < 16384) ? q : k;
    int b = (int)((m0 >> 11) & 7);
    int nbase = (int)(m0 & 2047);
    const float* xp = xsrc + ((size_t)b * CIN + wave * 4) * N_ + nbase + lane;

    f32x4 acc[4][4];
#pragma unroll
    for (int i = 0; i < 4; ++i)
#pragma unroll
        for (int j = 0; j < 4; ++j) acc[i][j] = (f32x4)0.f;

    for (int k0 = 0; k0 < CIN; k0 += 32) {
#pragma unroll
        for (int si = 0; si < 4; ++si) {
            int s = tid + si * 512;
            gload_lds16(W1b + (size_t)(s >> 2) * CIN + k0 + (s & 3) * 8, Bs + s * 8);
        }
        float v0 = xp[(size_t)(k0 + 0) * N_];
        float v1 = xp[(size_t)(k0 + 1) * N_];
        float v2 = xp[(size_t)(k0 + 2) * N_];
        float v3 = xp[(size_t)(k0 + 3) * N_];
        ushort4 wv;
        wv.x = f2bf(v0); wv.y = f2bf(v1); wv.z = f2bf(v2); wv.w = f2bf(v3);
        *(ushort4*)&As[lane * ASTRIDE + wave * 4] = wv;
        __syncthreads();

        short8 af[4], bfr[4];
#pragma unroll
        for (int mi = 0; mi < 4; ++mi)
            af[mi] = *(const short8*)&As[(mi * 16 + cl) * ASTRIDE + g * 8];
#pragma unroll
        for (int ni = 0; ni < 4; ++ni)
            bfr[ni] = *(const short8*)&Bs[(wave * 64 + ni * 16 + cl) * 32 + g * 8];
#pragma unroll
        for (int mi = 0; mi < 4; ++mi)
#pragma unroll
            for (int ni = 0; ni < 4; ++ni)
                acc[mi][ni] = __builtin_amdgcn_mfma_f32_16x16x32_bf16(af[mi], bfr[ni], acc[mi][ni], 0, 0, 0);
        __syncthreads();
    }

#pragma unroll
    for (int mi = 0; mi < 4; ++mi)
#pragma unroll
        for (int ni = 0; ni < 4; ++ni)
#pragma unroll
            for (int r = 0; r < 4; ++r) {
                float v = acc[mi][ni][r];
                v = (v >= 0.f) ? v : 0.01f * v;
                H[(m0 + mi * 16 + g * 4 + r) * CMID + wave * 64 + ni * 16 + cl] = f2bf(v);
            }
}

// ---------------- K2: conv2 fused with row L2-norm (fragment-layout output) ---------
__global__ __launch_bounds__(512) void conv2_norm(const ushort* __restrict__ H,
                                                  const ushort* __restrict__ W2b,
                                                  ushort* __restrict__ QK) {
    __shared__ ushort As[128 * 32];   // 8 KB
    __shared__ ushort Bs[256 * 32];   // 16 KB
    __shared__ float red[4][128];     // 2 KB
    int tid = threadIdx.x;
    int lane = tid & 63, wave = tid >> 6;
    int wm = wave >> 2, wn = wave & 3;
    int g = lane >> 4, cl = lane & 15;
    int bx = blockIdx.x;
    int half = bx >> 7;
    int u = bx & 127;
    int pb = u & 7, pj = u >> 3;          // pj in [0,16)
    size_t m0 = ((size_t)half * 128 + (size_t)pb * 16 + pj) * 128;

    f32x4 acc[4][4];
#pragma unroll
    for (int i = 0; i < 4; ++i)
#pragma unroll
        for (int j = 0; j < 4; ++j) acc[i][j] = (f32x4)0.f;

    for (int k0 = 0; k0 < CMID; k0 += 32) {
        gload_lds16(H + (m0 + (tid >> 2)) * CMID + k0 + (tid & 3) * 8, As + tid * 8);
#pragma unroll
        for (int si = 0; si < 2; ++si) {
            int s = tid + si * 512;
            gload_lds16(W2b + (size_t)(s >> 2) * CMID + k0 + (s & 3) * 8, Bs + s * 8);
        }
        __syncthreads();
        short8 af[4], bfr[4];
#pragma unroll
        for (int mi = 0; mi < 4; ++mi)
            af[mi] = *(const short8*)&As[(wm * 64 + mi * 16 + cl) * 32 + g * 8];
#pragma unroll
        for (int ni = 0; ni < 4; ++ni)
            bfr[ni] = *(const short8*)&Bs[(wn * 64 + ni * 16 + cl) * 32 + g * 8];
#pragma unroll
        for (int mi = 0; mi < 4; ++mi)
#pragma unroll
            for (int ni = 0; ni < 4; ++ni)
                acc[mi][ni] = __builtin_amdgcn_mfma_f32_16x16x32_bf16(af[mi], bfr[ni], acc[mi][ni], 0, 0, 0);
        __syncthreads();
    }

#pragma unroll
    for (int mi = 0; mi < 4; ++mi)
#pragma unroll
        for (int r = 0; r < 4; ++r) {
            float s = 0.f;
#pragma unroll
            for (int ni = 0; ni < 4; ++ni) { float v = acc[mi][ni][r]; s += v * v; }
#pragma unroll
            for (int off = 1; off < 16; off <<= 1) s += __shfl_xor(s, off, 64);
            if (cl == 0) red[wn][wm * 64 + mi * 16 + g * 4 + r] = s;
        }
    __syncthreads();
#pragma unroll
    for (int mi = 0; mi < 4; ++mi)
#pragma unroll
        for (int r = 0; r < 4; ++r) {
            int row = wm * 64 + mi * 16 + g * 4 + r;
            size_t row_g = m0 + row;
            float tot = red[0][row] + red[1][row] + red[2][row] + red[3][row];
            float inv = 1.0f / fmaxf(sqrtf(tot), NORM_EPS_);
            size_t pbase = (row_g >> 4) * 4096 + (size_t)(row_g & 15) * 8;
#pragma unroll
            for (int ni = 0; ni < 4; ++ni) {
                int kcol = wn * 64 + ni * 16 + cl;
                size_t off = pbase + (size_t)(kcol >> 5) * 512
                           + (size_t)((kcol >> 3) & 3) * 128 + (kcol & 7);
                QK[off] = f2bf(acc[mi][ni][r] * inv);
            }
        }
}

// ---------------- K3: pipelined scores + softmax(fixed max) + threshold -------------
// Persistent block = 64 q-rows as 4 groups of 16, double-buffered eLDS (2x66 KB).
// Group g's K-panel stream (L2 reads + MFMA + exp) hides group g-1's output
// stores (1 f32x4/thread interleaved per ct). af in registers (8 short8/group).
#define ESTRIDE 2052
__global__ __launch_bounds__(512, 2) void scores_softmax(const ushort* __restrict__ QK,
                                                         float* __restrict__ out) {
    __shared__ ushort eLDS[2][16 * ESTRIDE];   // 131328 B
    __shared__ float red[8][16];               // 512 B
    int bid = blockIdx.x;
    int b = bid & 7;                  // batch-per-XCD swizzle (256 blocks)
    int m0 = (bid >> 3) * 64;
    int tid = threadIdx.x;
    int lane = tid & 63, wave = tid >> 6;
    int g16 = lane >> 4, cl = lane & 15;

    const ushort* Kf = QK + ((size_t)(16384 + b * N_ + wave * 256) >> 4) * 4096;
    float* obase = out + (size_t)b * N_ * N_;
    int srow = wave * 2 + (lane >> 5);          // this thread's store row (0..15)
    int scol0 = (lane & 31) * 4;                // this thread's store col base
    int ecol = wave * 256 + cl;

    float inv_[2] = {0.f, 0.f};
    int prev_m = 0;

#pragma unroll
    for (int grp = 0; grp < 4; ++grp) {
        int gm = m0 + grp * 16;
        const ushort* Qf = QK + ((size_t)(b * N_ + gm) >> 4) * 4096;
        short8 af[8];
#pragma unroll
        for (int ks = 0; ks < 8; ++ks)
            af[ks] = *(const short8*)(Qf + ks * 512 + lane * 8);
        float rs[4] = {0.f, 0.f, 0.f, 0.f};
        ushort* ebuf = eLDS[grp & 1];
        const ushort* pbuf = eLDS[(grp & 1) ^ 1];

#pragma unroll
        for (int ct = 0; ct < 16; ++ct) {
            short8 bfr[8];
#pragma unroll
            for (int ks = 0; ks < 8; ++ks)
                bfr[ks] = *(const short8*)(Kf + (size_t)ct * 4096 + ks * 512 + lane * 8);
            // interleaved store of previous group's slice (independent of bfr)
            if (grp > 0) {
                int scol = ct * 128 + scol0;
                ushort4 ev = *(const ushort4*)&pbuf[srow * ESTRIDE + scol];
                float iv = inv_[lane >> 5];
                f32x4 w;
                float t;
                t = bf2f(ev.x) * iv; w.x = (t > EPS_THR) ? t : 0.f;
                t = bf2f(ev.y) * iv; w.y = (t > EPS_THR) ? t : 0.f;
                t = bf2f(ev.z) * iv; w.z = (t > EPS_THR) ? t : 0.f;
                t = bf2f(ev.w) * iv; w.w = (t > EPS_THR) ? t : 0.f;
                __builtin_nontemporal_store(w, (f32x4*)&obase[(size_t)(prev_m + srow) * N_ + scol]);
            }
            f32x4 a0 = (f32x4)0.f;
#pragma unroll
            for (int ks = 0; ks < 8; ++ks)
                a0 = __builtin_amdgcn_mfma_f32_16x16x32_bf16(af[ks], bfr[ks], a0, 0, 0, 0);
#pragma unroll
            for (int r = 0; r < 4; ++r) {
                float e0 = __expf((a0[r] - 1.0f) * SCALE_);
                rs[r] += e0;
                ebuf[(g16 * 4 + r) * ESTRIDE + ecol + ct * 16] = f2bf(e0);
            }
        }

        // row sums: reduce over 16 cl lanes, then across 8 waves via LDS
#pragma unroll
        for (int r = 0; r < 4; ++r) {
            float s = rs[r];
#pragma unroll
            for (int off = 1; off < 16; off <<= 1) s += __shfl_xor(s, off, 64);
            if (cl == 0) red[wave][g16 * 4 + r] = s;
        }
        __syncthreads();
#pragma unroll
        for (int rr = 0; rr < 2; ++rr) {
            int row = wave * 2 + rr;
            float t = 0.f;
#pragma unroll
            for (int w = 0; w < 8; ++w) t += red[w][row];
            inv_[rr] = 1.0f / t;
        }
        prev_m = gm;
        __syncthreads();   // red + eLDS buffer handoff
    }

    // epilogue: drain last group's stores
    const ushort* pbuf = eLDS[1];
    float iv = inv_[lane >> 5];
#pragma unroll
    for (int ct = 0; ct < 16; ++ct) {
        int scol = ct * 128 + scol0;
        ushort4 ev = *(const ushort4*)&pbuf[srow * ESTRIDE + scol];
        f32x4 w;
        float t;
        t = bf2f(ev.x) * iv; w.x = (t > EPS_THR) ? t : 0.f;
        t = bf2f(ev.y) * iv; w.y = (t > EPS_THR) ? t : 0.f;
        t = bf2f(ev.z) * iv; w.z = (t > EPS_THR) ? t : 0.f;
        t = bf2f(ev.w) * iv; w.w = (t > EPS_THR) ? t : 0.f;
        __builtin_nontemporal_store(w, (f32x4*)&obase[(size_t)(prev_m + srow) * N_ + scol]);
    }
}

// ---------------- K4: copy key to output tail ---------------------------------------
__global__ __launch_bounds__(256) void copy_key(const float* __restrict__ in,
                                                float* __restrict__ dst, int n4) {
    int i = blockIdx.x * 256 + threadIdx.x;
    if (i < n4) {
        f32x4 v = ((const f32x4*)in)[i];
        __builtin_nontemporal_store(v, &((f32x4*)dst)[i]);
    }
}

extern "C" void kernel_launch(void* const* d_in, const int* in_sizes, int n_in,
                              void* d_out, int out_size, void* d_ws, size_t ws_size,
                              hipStream_t stream) {
    const float* q  = (const float*)d_in[0];
    const float* k  = (const float*)d_in[1];
    const float* W1 = (const float*)d_in[2];
    const float* W2 = (const float*)d_in[3];
    float* out = (float*)d_out;

    // ws: W1b | W2b | QK  (17.3 MB)
    ushort* W1b = (ushort*)d_ws;
    ushort* W2b = W1b + 131072;
    ushort* QK  = W2b + 131072;                 // [2048 panels][4096] bf16 (fragment layout)

    // H scratch inside d_out (overwritten by scores_softmax later)
    ushort* H = (ushort*)d_out;                 // [32768][512] bf16, 33.5 MB

    prep_w<<<512, 256, 0, stream>>>(W1, W2, W1b, W2b);
    conv1_fused<<<512, 512, 0, stream>>>(q, k, W1b, H);
    conv2_norm<<<256, 512, 0, stream>>>(H, W2b, QK);
    scores_softmax<<<256, 512, 0, stream>>>(QK, out);
    copy_key<<<4096, 256, 0, stream>>>(k, out + (size_t)B_ * N_ * N_, (B_ * CIN * N_) / 4);
}

// Round 15
// 131.925 us; speedup vs baseline: 1.5992x; 1.5992x over previous
//
#include <hip/hip_runtime.h>
#include <hip/hip_bf16.h>
#include <math.h>

#define B_      8
#define CIN     256
#define CMID    512
#define COUT    256
#define N_      2048
#define SCALE_  10.0f
#define EPS_THR 1e-3f
#define NORM_EPS_ 1e-12f

typedef __attribute__((ext_vector_type(8))) short short8;
typedef __attribute__((ext_vector_type(4))) float f32x4;

__device__ __forceinline__ ushort f2bf(float x) {
    union { float f; uint u; } v; v.f = x;
    uint r = v.u + 0x7FFF + ((v.u >> 16) & 1);
    return (ushort)(r >> 16);
}
__device__ __forceinline__ void gload_lds16(const void* g, void* l) {
    __builtin_amdgcn_global_load_lds((const __attribute__((address_space(1))) void*)g,
                                     (__attribute__((address_space(3))) void*)l, 16, 0, 0);
}

// ---------------- K0: weights fp32 -> bf16 ------------------------------------------
__global__ __launch_bounds__(256) void prep_w(const float* __restrict__ W1,
                                              const float* __restrict__ W2,
                                              ushort* __restrict__ W1b,
                                              ushort* __restrict__ W2b) {
    int idx = blockIdx.x * 256 + threadIdx.x;   // 0..131071
    W1b[idx] = f2bf(W1[idx]);
    W2b[idx] = f2bf(W2[idx]);
}

// ---------------- K1: conv1 fused with input transpose ------------------------------
#define ASTRIDE 40
__global__ __launch_bounds__(512) void conv1_fused(const float* __restrict__ q,
                                                   const float* __restrict__ k,
                                                   const ushort* __restrict__ W1b,
                                                   ushort* __restrict__ H) {
    __shared__ ushort As[64 * ASTRIDE];   // 5 KB, padded stride
    __shared__ ushort Bs[512 * 32];       // 32 KB
    int tid = threadIdx.x;
    int lane = tid & 63, wave = tid >> 6;
    int g = lane >> 4, cl = lane & 15;
    int bx = blockIdx.x;
    int half = bx >> 8;
    int u = bx & 255;
    int pb = u & 7, pj = u >> 3;          // pj in [0,32)
    size_t m0 = ((size_t)half * 256 + (size_t)pb * 32 + pj) * 64;
    const float* xsrc = (m0 < 16384) ? q : k;
    int b = (int)((m0 >> 11) & 7);
    int nbase = (int)(m0 & 2047);
    const float* xp = xsrc + ((size_t)b * CIN + wave * 4) * N_ + nbase + lane;

    f32x4 acc[4][4];
#pragma unroll
    for (int i = 0; i < 4; ++i)
#pragma unroll
        for (int j = 0; j < 4; ++j) acc[i][j] = (f32x4)0.f;

    for (int k0 = 0; k0 < CIN; k0 += 32) {
#pragma unroll
        for (int si = 0; si < 4; ++si) {
            int s = tid + si * 512;
            gload_lds16(W1b + (size_t)(s >> 2) * CIN + k0 + (s & 3) * 8, Bs + s * 8);
        }
        float v0 = xp[(size_t)(k0 + 0) * N_];
        float v1 = xp[(size_t)(k0 + 1) * N_];
        float v2 = xp[(size_t)(k0 + 2) * N_];
        float v3 = xp[(size_t)(k0 + 3) * N_];
        ushort4 wv;
        wv.x = f2bf(v0); wv.y = f2bf(v1); wv.z = f2bf(v2); wv.w = f2bf(v3);
        *(ushort4*)&As[lane * ASTRIDE + wave * 4] = wv;
        __syncthreads();

        short8 af[4], bfr[4];
#pragma unroll
        for (int mi = 0; mi < 4; ++mi)
            af[mi] = *(const short8*)&As[(mi * 16 + cl) * ASTRIDE + g * 8];
#pragma unroll
        for (int ni = 0; ni < 4; ++ni)
            bfr[ni] = *(const short8*)&Bs[(wave * 64 + ni * 16 + cl) * 32 + g * 8];
#pragma unroll
        for (int mi = 0; mi < 4; ++mi)
#pragma unroll
            for (int ni = 0; ni < 4; ++ni)
                acc[mi][ni] = __builtin_amdgcn_mfma_f32_16x16x32_bf16(af[mi], bfr[ni], acc[mi][ni], 0, 0, 0);
        __syncthreads();
    }

#pragma unroll
    for (int mi = 0; mi < 4; ++mi)
#pragma unroll
        for (int ni = 0; ni < 4; ++ni)
#pragma unroll
            for (int r = 0; r < 4; ++r) {
                float v = acc[mi][ni][r];
                v = (v >= 0.f) ? v : 0.01f * v;
                H[(m0 + mi * 16 + g * 4 + r) * CMID + wave * 64 + ni * 16 + cl] = f2bf(v);
            }
}

// ---------------- K2: conv2 fused with row L2-norm (fragment-layout output) ---------
// Element (row, kcol) stored at
//   (row>>4)*4096 + (kcol>>5)*512 + ((kcol>>3)&3)*128 + (row&15)*8 + (kcol&7)
__global__ __launch_bounds__(512) void conv2_norm(const ushort* __restrict__ H,
                                                  const ushort* __restrict__ W2b,
                                                  ushort* __restrict__ QK) {
    __shared__ ushort As[128 * 32];   // 8 KB
    __shared__ ushort Bs[256 * 32];   // 16 KB
    __shared__ float red[4][128];     // 2 KB
    int tid = threadIdx.x;
    int lane = tid & 63, wave = tid >> 6;
    int wm = wave >> 2, wn = wave & 3;
    int g = lane >> 4, cl = lane & 15;
    int bx = blockIdx.x;
    int half = bx >> 7;
    int u = bx & 127;
    int pb = u & 7, pj = u >> 3;          // pj in [0,16)
    size_t m0 = ((size_t)half * 128 + (size_t)pb * 16 + pj) * 128;

    f32x4 acc[4][4];
#pragma unroll
    for (int i = 0; i < 4; ++i)
#pragma unroll
        for (int j = 0; j < 4; ++j) acc[i][j] = (f32x4)0.f;

    for (int k0 = 0; k0 < CMID; k0 += 32) {
        gload_lds16(H + (m0 + (tid >> 2)) * CMID + k0 + (tid & 3) * 8, As + tid * 8);
#pragma unroll
        for (int si = 0; si < 2; ++si) {
            int s = tid + si * 512;
            gload_lds16(W2b + (size_t)(s >> 2) * CMID + k0 + (s & 3) * 8, Bs + s * 8);
        }
        __syncthreads();
        short8 af[4], bfr[4];
#pragma unroll
        for (int mi = 0; mi < 4; ++mi)
            af[mi] = *(const short8*)&As[(wm * 64 + mi * 16 + cl) * 32 + g * 8];
#pragma unroll
        for (int ni = 0; ni < 4; ++ni)
            bfr[ni] = *(const short8*)&Bs[(wn * 64 + ni * 16 + cl) * 32 + g * 8];
#pragma unroll
        for (int mi = 0; mi < 4; ++mi)
#pragma unroll
            for (int ni = 0; ni < 4; ++ni)
                acc[mi][ni] = __builtin_amdgcn_mfma_f32_16x16x32_bf16(af[mi], bfr[ni], acc[mi][ni], 0, 0, 0);
        __syncthreads();
    }

#pragma unroll
    for (int mi = 0; mi < 4; ++mi)
#pragma unroll
        for (int r = 0; r < 4; ++r) {
            float s = 0.f;
#pragma unroll
            for (int ni = 0; ni < 4; ++ni) { float v = acc[mi][ni][r]; s += v * v; }
#pragma unroll
            for (int off = 1; off < 16; off <<= 1) s += __shfl_xor(s, off, 64);
            if (cl == 0) red[wn][wm * 64 + mi * 16 + g * 4 + r] = s;
        }
    __syncthreads();
#pragma unroll
    for (int mi = 0; mi < 4; ++mi)
#pragma unroll
        for (int r = 0; r < 4; ++r) {
            int row = wm * 64 + mi * 16 + g * 4 + r;
            size_t row_g = m0 + row;
            float tot = red[0][row] + red[1][row] + red[2][row] + red[3][row];
            float inv = 1.0f / fmaxf(sqrtf(tot), NORM_EPS_);
            size_t pbase = (row_g >> 4) * 4096 + (size_t)(row_g & 15) * 8;
#pragma unroll
            for (int ni = 0; ni < 4; ++ni) {
                int kcol = wn * 64 + ni * 16 + cl;
                size_t off = pbase + (size_t)(kcol >> 5) * 512
                           + (size_t)((kcol >> 3) & 3) * 128 + (kcol & 7);
                QK[off] = f2bf(acc[mi][ni][r] * inv);
            }
        }
}

// ---------------- K3: two-pass scores + softmax(fixed max) + threshold --------------
// 32 q-rows x 2048 k-cols per block, 512 blocks, ZERO eLDS. af resident in regs
// (64 VGPR); pass 1 streams K-panel (L2-hot, shared by all 64 blocks of the XCD)
// -> row sums; pass 2 re-streams, recomputes MFMA+exp, scales, thresholds, stores
// from registers. ~127 VGPR, 1 KB LDS -> 2 blocks/CU at independent phases: one
// block's stores overlap the other's reads without lockstep.
__global__ __launch_bounds__(512, 2) void scores_softmax(const ushort* __restrict__ QK,
                                                         float* __restrict__ out) {
    __shared__ float red[8][32];     // 1 KB
    int bid = blockIdx.x;
    int b = bid & 7;                 // batch-per-XCD swizzle
    int m0 = (bid >> 3) * 32;
    int tid = threadIdx.x;
    int lane = tid & 63, wave = tid >> 6;
    int g = lane >> 4, cl = lane & 15;

    const ushort* Qf = QK + ((size_t)(b * N_ + m0) >> 4) * 4096;
    const ushort* Kf = QK + ((size_t)(16384 + b * N_ + wave * 256) >> 4) * 4096;

    short8 af0[8], af1[8];           // 64 VGPR resident
#pragma unroll
    for (int ks = 0; ks < 8; ++ks) {
        af0[ks] = *(const short8*)(Qf + ks * 512 + lane * 8);
        af1[ks] = *(const short8*)(Qf + 4096 + ks * 512 + lane * 8);
    }

    float rs0[4] = {0.f, 0.f, 0.f, 0.f}, rs1[4] = {0.f, 0.f, 0.f, 0.f};

    // ---- pass 1: row sums only ----
    for (int ct = 0; ct < 16; ++ct) {
        short8 bfr[8];
#pragma unroll
        for (int ks = 0; ks < 8; ++ks)
            bfr[ks] = *(const short8*)(Kf + (size_t)ct * 4096 + ks * 512 + lane * 8);
        f32x4 a0 = (f32x4)0.f, a1 = (f32x4)0.f;
#pragma unroll
        for (int ks = 0; ks < 8; ++ks) {
            a0 = __builtin_amdgcn_mfma_f32_16x16x32_bf16(af0[ks], bfr[ks], a0, 0, 0, 0);
            a1 = __builtin_amdgcn_mfma_f32_16x16x32_bf16(af1[ks], bfr[ks], a1, 0, 0, 0);
        }
#pragma unroll
        for (int r = 0; r < 4; ++r) {
            rs0[r] += __expf((a0[r] - 1.0f) * SCALE_);
            rs1[r] += __expf((a1[r] - 1.0f) * SCALE_);
        }
    }

    // reduce over 16 cl lanes, then across 8 waves via LDS
#pragma unroll
    for (int r = 0; r < 4; ++r) {
        float s = rs0[r];
#pragma unroll
        for (int off = 1; off < 16; off <<= 1) s += __shfl_xor(s, off, 64);
        if (cl == 0) red[wave][g * 4 + r] = s;
        float s1 = rs1[r];
#pragma unroll
        for (int off = 1; off < 16; off <<= 1) s1 += __shfl_xor(s1, off, 64);
        if (cl == 0) red[wave][16 + g * 4 + r] = s1;
    }
    __syncthreads();

    float inv0[4], inv1[4];
#pragma unroll
    for (int r = 0; r < 4; ++r) {
        int row = g * 4 + r;
        float t0 = 0.f, t1 = 0.f;
#pragma unroll
        for (int w = 0; w < 8; ++w) { t0 += red[w][row]; t1 += red[w][16 + row]; }
        inv0[r] = 1.0f / t0;
        inv1[r] = 1.0f / t1;
    }

    // ---- pass 2: recompute (K-panel L2-hot), scale, threshold, store ----
    float* ob = out + (size_t)b * N_ * N_ + (size_t)m0 * N_ + wave * 256;
    for (int ct = 0; ct < 16; ++ct) {
        short8 bfr[8];
#pragma unroll
        for (int ks = 0; ks < 8; ++ks)
            bfr[ks] = *(const short8*)(Kf + (size_t)ct * 4096 + ks * 512 + lane * 8);
        f32x4 a0 = (f32x4)0.f, a1 = (f32x4)0.f;
#pragma unroll
        for (int ks = 0; ks < 8; ++ks) {
            a0 = __builtin_amdgcn_mfma_f32_16x16x32_bf16(af0[ks], bfr[ks], a0, 0, 0, 0);
            a1 = __builtin_amdgcn_mfma_f32_16x16x32_bf16(af1[ks], bfr[ks], a1, 0, 0, 0);
        }
#pragma unroll
        for (int r = 0; r < 4; ++r) {
            float w0 = __expf((a0[r] - 1.0f) * SCALE_) * inv0[r];
            w0 = (w0 > EPS_THR) ? w0 : 0.f;
            __builtin_nontemporal_store(w0, &ob[(size_t)(g * 4 + r) * N_ + ct * 16 + cl]);
            float w1 = __expf((a1[r] - 1.0f) * SCALE_) * inv1[r];
            w1 = (w1 > EPS_THR) ? w1 : 0.f;
            __builtin_nontemporal_store(w1, &ob[(size_t)(16 + g * 4 + r) * N_ + ct * 16 + cl]);
        }
    }
}

// ---------------- K4: copy key to output tail ---------------------------------------
__global__ __launch_bounds__(256) void copy_key(const float* __restrict__ in,
                                                float* __restrict__ dst, int n4) {
    int i = blockIdx.x * 256 + threadIdx.x;
    if (i < n4) {
        f32x4 v = ((const f32x4*)in)[i];
        __builtin_nontemporal_store(v, &((f32x4*)dst)[i]);
    }
}

extern "C" void kernel_launch(void* const* d_in, const int* in_sizes, int n_in,
                              void* d_out, int out_size, void* d_ws, size_t ws_size,
                              hipStream_t stream) {
    const float* q  = (const float*)d_in[0];
    const float* k  = (const float*)d_in[1];
    const float* W1 = (const float*)d_in[2];
    const float* W2 = (const float*)d_in[3];
    float* out = (float*)d_out;

    // ws: W1b | W2b | QK  (17.3 MB)
    ushort* W1b = (ushort*)d_ws;
    ushort* W2b = W1b + 131072;
    ushort* QK  = W2b + 131072;                 // [2048 panels][4096] bf16 (fragment layout)

    // H scratch inside d_out (overwritten by scores_softmax later)
    ushort* H = (ushort*)d_out;                 // [32768][512] bf16, 33.5 MB

    prep_w<<<512, 256, 0, stream>>>(W1, W2, W1b, W2b);
    conv1_fused<<<512, 512, 0, stream>>>(q, k, W1b, H);
    conv2_norm<<<256, 512, 0, stream>>>(H, W2b, QK);
    scores_softmax<<<512, 512, 0, stream>>>(QK, out);
    copy_key<<<4096, 256, 0, stream>>>(k, out + (size_t)B_ * N_ * N_, (B_ * CIN * N_) / 4);
}

// Round 16
// 106.321 us; speedup vs baseline: 1.9843x; 1.2408x over previous
//
#include <hip/hip_runtime.h>
#include <hip/hip_bf16.h>
#include <math.h>

#define B_      8
#define CIN     256
#define CMID    512
#define COUT    256
#define N_      2048
#define SCALE_  10.0f
#define EPS_THR 1e-3f
#define NORM_EPS_ 1e-12f

typedef __attribute__((ext_vector_type(8))) short short8;
typedef __attribute__((ext_vector_type(4))) float f32x4;

__device__ __forceinline__ ushort f2bf(float x) {
    union { float f; uint u; } v; v.f = x;
    uint r = v.u + 0x7FFF + ((v.u >> 16) & 1);
    return (ushort)(r >> 16);
}
__device__ __forceinline__ float bf2f(ushort h) {
    union { uint u; float f; } v; v.u = ((uint)h) << 16;
    return v.f;
}
__device__ __forceinline__ void gload_lds16(const void* g, void* l) {
    __builtin_amdgcn_global_load_lds((const __attribute__((address_space(1))) void*)g,
                                     (__attribute__((address_space(3))) void*)l, 16, 0, 0);
}

// ---------------- K0: weights fp32 -> bf16 ------------------------------------------
__global__ __launch_bounds__(256) void prep_w(const float* __restrict__ W1,
                                              const float* __restrict__ W2,
                                              ushort* __restrict__ W1b,
                                              ushort* __restrict__ W2b) {
    int idx = blockIdx.x * 256 + threadIdx.x;   // 0..131071
    W1b[idx] = f2bf(W1[idx]);
    W2b[idx] = f2bf(W2[idx]);
}

// ---------------- K1: conv1 + input transpose + fused key tail copy -----------------
#define ASTRIDE 40
__global__ __launch_bounds__(512) void conv1_fused(const float* __restrict__ q,
                                                   const float* __restrict__ k,
                                                   const ushort* __restrict__ W1b,
                                                   ushort* __restrict__ H,
                                                   float* __restrict__ tail) {
    __shared__ ushort As[64 * ASTRIDE];   // 5 KB, padded stride
    __shared__ ushort Bs[512 * 32];       // 32 KB
    int tid = threadIdx.x;
    int lane = tid & 63, wave = tid >> 6;
    int g = lane >> 4, cl = lane & 15;
    int bx = blockIdx.x;
    int half = bx >> 8;
    int u = bx & 255;
    int pb = u & 7, pj = u >> 3;          // pj in [0,32)
    size_t m0 = ((size_t)half * 256 + (size_t)pb * 32 + pj) * 64;
    const int is_k = (m0 >= 16384);
    const float* xsrc = is_k ? k : q;
    int b = (int)((m0 >> 11) & 7);
    int nbase = (int)(m0 & 2047);
    const size_t xoff = ((size_t)b * CIN + wave * 4) * N_ + nbase + lane;
    const float* xp = xsrc + xoff;

    f32x4 acc[4][4];
#pragma unroll
    for (int i = 0; i < 4; ++i)
#pragma unroll
        for (int j = 0; j < 4; ++j) acc[i][j] = (f32x4)0.f;

    for (int k0 = 0; k0 < CIN; k0 += 32) {
#pragma unroll
        for (int si = 0; si < 4; ++si) {
            int s = tid + si * 512;
            gload_lds16(W1b + (size_t)(s >> 2) * CIN + k0 + (s & 3) * 8, Bs + s * 8);
        }
        float v0 = xp[(size_t)(k0 + 0) * N_];
        float v1 = xp[(size_t)(k0 + 1) * N_];
        float v2 = xp[(size_t)(k0 + 2) * N_];
        float v3 = xp[(size_t)(k0 + 3) * N_];
        if (is_k) {   // fused key -> output-tail copy (same bytes, same layout)
            __builtin_nontemporal_store(v0, tail + xoff + (size_t)(k0 + 0) * N_);
            __builtin_nontemporal_store(v1, tail + xoff + (size_t)(k0 + 1) * N_);
            __builtin_nontemporal_store(v2, tail + xoff + (size_t)(k0 + 2) * N_);
            __builtin_nontemporal_store(v3, tail + xoff + (size_t)(k0 + 3) * N_);
        }
        ushort4 wv;
        wv.x = f2bf(v0); wv.y = f2bf(v1); wv.z = f2bf(v2); wv.w = f2bf(v3);
        *(ushort4*)&As[lane * ASTRIDE + wave * 4] = wv;
        __syncthreads();

        short8 af[4], bfr[4];
#pragma unroll
        for (int mi = 0; mi < 4; ++mi)
            af[mi] = *(const short8*)&As[(mi * 16 + cl) * ASTRIDE + g * 8];
#pragma unroll
        for (int ni = 0; ni < 4; ++ni)
            bfr[ni] = *(const short8*)&Bs[(wave * 64 + ni * 16 + cl) * 32 + g * 8];
#pragma unroll
        for (int mi = 0; mi < 4; ++mi)
#pragma unroll
            for (int ni = 0; ni < 4; ++ni)
                acc[mi][ni] = __builtin_amdgcn_mfma_f32_16x16x32_bf16(af[mi], bfr[ni], acc[mi][ni], 0, 0, 0);
        __syncthreads();
    }

#pragma unroll
    for (int mi = 0; mi < 4; ++mi)
#pragma unroll
        for (int ni = 0; ni < 4; ++ni)
#pragma unroll
            for (int r = 0; r < 4; ++r) {
                float v = acc[mi][ni][r];
                v = (v >= 0.f) ? v : 0.01f * v;
                H[(m0 + mi * 16 + g * 4 + r) * CMID + wave * 64 + ni * 16 + cl] = f2bf(v);
            }
}

// ---------------- K2: conv2 fused with row L2-norm (fragment-layout output) ---------
// Element (row, kcol) stored at
//   (row>>4)*4096 + (kcol>>5)*512 + ((kcol>>3)&3)*128 + (row&15)*8 + (kcol&7)
__global__ __launch_bounds__(512) void conv2_norm(const ushort* __restrict__ H,
                                                  const ushort* __restrict__ W2b,
                                                  ushort* __restrict__ QK) {
    __shared__ ushort As[128 * 32];   // 8 KB
    __shared__ ushort Bs[256 * 32];   // 16 KB
    __shared__ float red[4][128];     // 2 KB
    int tid = threadIdx.x;
    int lane = tid & 63, wave = tid >> 6;
    int wm = wave >> 2, wn = wave & 3;
    int g = lane >> 4, cl = lane & 15;
    int bx = blockIdx.x;
    int half = bx >> 7;
    int u = bx & 127;
    int pb = u & 7, pj = u >> 3;          // pj in [0,16)
    size_t m0 = ((size_t)half * 128 + (size_t)pb * 16 + pj) * 128;

    f32x4 acc[4][4];
#pragma unroll
    for (int i = 0; i < 4; ++i)
#pragma unroll
        for (int j = 0; j < 4; ++j) acc[i][j] = (f32x4)0.f;

    for (int k0 = 0; k0 < CMID; k0 += 32) {
        gload_lds16(H + (m0 + (tid >> 2)) * CMID + k0 + (tid & 3) * 8, As + tid * 8);
#pragma unroll
        for (int si = 0; si < 2; ++si) {
            int s = tid + si * 512;
            gload_lds16(W2b + (size_t)(s >> 2) * CMID + k0 + (s & 3) * 8, Bs + s * 8);
        }
        __syncthreads();
        short8 af[4], bfr[4];
#pragma unroll
        for (int mi = 0; mi < 4; ++mi)
            af[mi] = *(const short8*)&As[(wm * 64 + mi * 16 + cl) * 32 + g * 8];
#pragma unroll
        for (int ni = 0; ni < 4; ++ni)
            bfr[ni] = *(const short8*)&Bs[(wn * 64 + ni * 16 + cl) * 32 + g * 8];
#pragma unroll
        for (int mi = 0; mi < 4; ++mi)
#pragma unroll
            for (int ni = 0; ni < 4; ++ni)
                acc[mi][ni] = __builtin_amdgcn_mfma_f32_16x16x32_bf16(af[mi], bfr[ni], acc[mi][ni], 0, 0, 0);
        __syncthreads();
    }

#pragma unroll
    for (int mi = 0; mi < 4; ++mi)
#pragma unroll
        for (int r = 0; r < 4; ++r) {
            float s = 0.f;
#pragma unroll
            for (int ni = 0; ni < 4; ++ni) { float v = acc[mi][ni][r]; s += v * v; }
#pragma unroll
            for (int off = 1; off < 16; off <<= 1) s += __shfl_xor(s, off, 64);
            if (cl == 0) red[wn][wm * 64 + mi * 16 + g * 4 + r] = s;
        }
    __syncthreads();
#pragma unroll
    for (int mi = 0; mi < 4; ++mi)
#pragma unroll
        for (int r = 0; r < 4; ++r) {
            int row = wm * 64 + mi * 16 + g * 4 + r;
            size_t row_g = m0 + row;
            float tot = red[0][row] + red[1][row] + red[2][row] + red[3][row];
            float inv = 1.0f / fmaxf(sqrtf(tot), NORM_EPS_);
            size_t pbase = (row_g >> 4) * 4096 + (size_t)(row_g & 15) * 8;
#pragma unroll
            for (int ni = 0; ni < 4; ++ni) {
                int kcol = wn * 64 + ni * 16 + cl;
                size_t off = pbase + (size_t)(kcol >> 5) * 512
                           + (size_t)((kcol >> 3) & 3) * 128 + (kcol & 7);
                QK[off] = f2bf(acc[mi][ni][r] * inv);
            }
        }
}

// ---------------- K3: fused scores + softmax(fixed max) + threshold (R12/best) ------
// 32 q-rows x 2048 k-cols per block (512 blocks), 8 waves. Fragment-layout QK =>
// af/bfr loads are contiguous 1 KB wave transactions. e staged in LDS bf16.
#define ESTRIDE 2052
__global__ __launch_bounds__(512, 2) void scores_softmax(const ushort* __restrict__ QK,
                                                         float* __restrict__ out) {
    __shared__ ushort eLDS[32 * ESTRIDE];   // 131328 B
    __shared__ float red[8][32];            // 1 KB
    int bid = blockIdx.x;
    int b = bid & 7;                 // batch-per-XCD swizzle
    int m0 = (bid >> 3) * 32;
    int tid = threadIdx.x;
    int lane = tid & 63, wave = tid >> 6;
    int g = lane >> 4, cl = lane & 15;

    const ushort* Qf = QK + ((size_t)(b * N_ + m0) >> 4) * 4096;
    const ushort* Kf = QK + ((size_t)(16384 + b * N_ + wave * 256) >> 4) * 4096;

    short8 af0[8], af1[8];
#pragma unroll
    for (int ks = 0; ks < 8; ++ks) {
        af0[ks] = *(const short8*)(Qf + ks * 512 + lane * 8);
        af1[ks] = *(const short8*)(Qf + 4096 + ks * 512 + lane * 8);
    }

    float rs0[4] = {0.f, 0.f, 0.f, 0.f}, rs1[4] = {0.f, 0.f, 0.f, 0.f};
    int ecol = wave * 256 + cl;

    short8 bfr[2][8];
#pragma unroll
    for (int ks = 0; ks < 8; ++ks)
        bfr[0][ks] = *(const short8*)(Kf + ks * 512 + lane * 8);

#pragma unroll
    for (int ct = 0; ct < 16; ++ct) {
        const int cur = ct & 1, nxt = cur ^ 1;
        if (ct < 15) {
#pragma unroll
            for (int ks = 0; ks < 8; ++ks)
                bfr[nxt][ks] = *(const short8*)(Kf + (size_t)(ct + 1) * 4096 + ks * 512 + lane * 8);
        }
        f32x4 a0 = (f32x4)0.f, a1 = (f32x4)0.f;
#pragma unroll
        for (int ks = 0; ks < 8; ++ks) {
            a0 = __builtin_amdgcn_mfma_f32_16x16x32_bf16(af0[ks], bfr[cur][ks], a0, 0, 0, 0);
            a1 = __builtin_amdgcn_mfma_f32_16x16x32_bf16(af1[ks], bfr[cur][ks], a1, 0, 0, 0);
        }
#pragma unroll
        for (int r = 0; r < 4; ++r) {
            float e0 = __expf((a0[r] - 1.0f) * SCALE_);
            rs0[r] += e0;
            eLDS[(g * 4 + r) * ESTRIDE + ecol + ct * 16] = f2bf(e0);
            float e1 = __expf((a1[r] - 1.0f) * SCALE_);
            rs1[r] += e1;
            eLDS[(16 + g * 4 + r) * ESTRIDE + ecol + ct * 16] = f2bf(e1);
        }
    }

    // row sums: reduce over 16 cl lanes, then across 8 waves via LDS
#pragma unroll
    for (int r = 0; r < 4; ++r) {
        float s = rs0[r];
#pragma unroll
        for (int off = 1; off < 16; off <<= 1) s += __shfl_xor(s, off, 64);
        if (cl == 0) red[wave][g * 4 + r] = s;
        float s1 = rs1[r];
#pragma unroll
        for (int off = 1; off < 16; off <<= 1) s1 += __shfl_xor(s1, off, 64);
        if (cl == 0) red[wave][16 + g * 4 + r] = s1;
    }
    __syncthreads();

    // phase 2: wave w -> rows 4w..4w+3; scale, threshold, store
    float inv_[4];
#pragma unroll
    for (int rr = 0; rr < 4; ++rr) {
        int row = wave * 4 + rr;
        float t = 0.f;
#pragma unroll
        for (int w = 0; w < 8; ++w) t += red[w][row];
        inv_[rr] = 1.0f / t;
    }

    float* ob = out + (size_t)b * N_ * N_ + (size_t)m0 * N_;
#pragma unroll
    for (int rr = 0; rr < 4; ++rr) {
        int row = wave * 4 + rr;
        const ushort* ep = &eLDS[row * ESTRIDE];
        float* orow = ob + (size_t)row * N_;
#pragma unroll
        for (int j = 0; j < 8; ++j) {
            int c = j * 256 + lane * 4;
            ushort4 ev = *(const ushort4*)&ep[c];
            f32x4 w;
            float t;
            t = bf2f(ev.x) * inv_[rr]; w.x = (t > EPS_THR) ? t : 0.f;
            t = bf2f(ev.y) * inv_[rr]; w.y = (t > EPS_THR) ? t : 0.f;
            t = bf2f(ev.z) * inv_[rr]; w.z = (t > EPS_THR) ? t : 0.f;
            t = bf2f(ev.w) * inv_[rr]; w.w = (t > EPS_THR) ? t : 0.f;
            __builtin_nontemporal_store(w, (f32x4*)&orow[c]);
        }
    }
}

extern "C" void kernel_launch(void* const* d_in, const int* in_sizes, int n_in,
                              void* d_out, int out_size, void* d_ws, size_t ws_size,
                              hipStream_t stream) {
    const float* q  = (const float*)d_in[0];
    const float* k  = (const float*)d_in[1];
    const float* W1 = (const float*)d_in[2];
    const float* W2 = (const float*)d_in[3];
    float* out = (float*)d_out;

    // ws: W1b | W2b | QK  (17.3 MB)
    ushort* W1b = (ushort*)d_ws;
    ushort* W2b = W1b + 131072;
    ushort* QK  = W2b + 131072;                 // [2048 panels][4096] bf16 (fragment layout)

    // H scratch inside d_out (overwritten by scores_softmax later)
    ushort* H = (ushort*)d_out;                 // [32768][512] bf16, 33.5 MB
    float* tail = out + (size_t)B_ * N_ * N_;   // key copy destination

    prep_w<<<512, 256, 0, stream>>>(W1, W2, W1b, W2b);
    conv1_fused<<<512, 512, 0, stream>>>(q, k, W1b, H, tail);
    conv2_norm<<<256, 512, 0, stream>>>(H, W2b, QK);
    scores_softmax<<<512, 512, 0, stream>>>(QK, out);
}

// Round 17
// 103.422 us; speedup vs baseline: 2.0399x; 1.0280x over previous
//
#include <hip/hip_runtime.h>
#include <hip/hip_bf16.h>
#include <math.h>

#define B_      8
#define CIN     256
#define CMID    512
#define COUT    256
#define N_      2048
#define SCALE_  10.0f
#define EPS_THR 1e-3f
#define NORM_EPS_ 1e-12f

typedef __attribute__((ext_vector_type(8))) short short8;
typedef __attribute__((ext_vector_type(4))) float f32x4;

__device__ __forceinline__ ushort f2bf(float x) {
    union { float f; uint u; } v; v.f = x;
    uint r = v.u + 0x7FFF + ((v.u >> 16) & 1);
    return (ushort)(r >> 16);
}
__device__ __forceinline__ float bf2f(ushort h) {
    union { uint u; float f; } v; v.u = ((uint)h) << 16;
    return v.f;
}
__device__ __forceinline__ void gload_lds16(const void* g, void* l) {
    __builtin_amdgcn_global_load_lds((const __attribute__((address_space(1))) void*)g,
                                     (__attribute__((address_space(3))) void*)l, 16, 0, 0);
}

// ---------------- K0: weights fp32 -> bf16 ------------------------------------------
__global__ __launch_bounds__(256) void prep_w(const float* __restrict__ W1,
                                              const float* __restrict__ W2,
                                              ushort* __restrict__ W1b,
                                              ushort* __restrict__ W2b) {
    int idx = blockIdx.x * 256 + threadIdx.x;   // 0..131071
    W1b[idx] = f2bf(W1[idx]);
    W2b[idx] = f2bf(W2[idx]);
}

// ---------------- K1: conv1 + input transpose + fused key tail copy -----------------
#define ASTRIDE 40
__global__ __launch_bounds__(512) void conv1_fused(const float* __restrict__ q,
                                                   const float* __restrict__ k,
                                                   const ushort* __restrict__ W1b,
                                                   ushort* __restrict__ H,
                                                   float* __restrict__ tail) {
    __shared__ ushort As[64 * ASTRIDE];   // 5 KB, padded stride
    __shared__ ushort Bs[512 * 32];       // 32 KB
    int tid = threadIdx.x;
    int lane = tid & 63, wave = tid >> 6;
    int g = lane >> 4, cl = lane & 15;
    int bx = blockIdx.x;
    int half = bx >> 8;
    int u = bx & 255;
    int pb = u & 7, pj = u >> 3;          // pj in [0,32)
    size_t m0 = ((size_t)half * 256 + (size_t)pb * 32 + pj) * 64;
    const int is_k = (m0 >= 16384);
    const float* xsrc = is_k ? k : q;
    int b = (int)((m0 >> 11) & 7);
    int nbase = (int)(m0 & 2047);
    const size_t xoff = ((size_t)b * CIN + wave * 4) * N_ + nbase + lane;
    const float* xp = xsrc + xoff;

    f32x4 acc[4][4];
#pragma unroll
    for (int i = 0; i < 4; ++i)
#pragma unroll
        for (int j = 0; j < 4; ++j) acc[i][j] = (f32x4)0.f;

    for (int k0 = 0; k0 < CIN; k0 += 32) {
#pragma unroll
        for (int si = 0; si < 4; ++si) {
            int s = tid + si * 512;
            gload_lds16(W1b + (size_t)(s >> 2) * CIN + k0 + (s & 3) * 8, Bs + s * 8);
        }
        float v0 = xp[(size_t)(k0 + 0) * N_];
        float v1 = xp[(size_t)(k0 + 1) * N_];
        float v2 = xp[(size_t)(k0 + 2) * N_];
        float v3 = xp[(size_t)(k0 + 3) * N_];
        if (is_k) {   // fused key -> output-tail copy (same bytes, same layout)
            __builtin_nontemporal_store(v0, tail + xoff + (size_t)(k0 + 0) * N_);
            __builtin_nontemporal_store(v1, tail + xoff + (size_t)(k0 + 1) * N_);
            __builtin_nontemporal_store(v2, tail + xoff + (size_t)(k0 + 2) * N_);
            __builtin_nontemporal_store(v3, tail + xoff + (size_t)(k0 + 3) * N_);
        }
        ushort4 wv;
        wv.x = f2bf(v0); wv.y = f2bf(v1); wv.z = f2bf(v2); wv.w = f2bf(v3);
        *(ushort4*)&As[lane * ASTRIDE + wave * 4] = wv;
        __syncthreads();

        short8 af[4], bfr[4];
#pragma unroll
        for (int mi = 0; mi < 4; ++mi)
            af[mi] = *(const short8*)&As[(mi * 16 + cl) * ASTRIDE + g * 8];
#pragma unroll
        for (int ni = 0; ni < 4; ++ni)
            bfr[ni] = *(const short8*)&Bs[(wave * 64 + ni * 16 + cl) * 32 + g * 8];
#pragma unroll
        for (int mi = 0; mi < 4; ++mi)
#pragma unroll
            for (int ni = 0; ni < 4; ++ni)
                acc[mi][ni] = __builtin_amdgcn_mfma_f32_16x16x32_bf16(af[mi], bfr[ni], acc[mi][ni], 0, 0, 0);
        __syncthreads();
    }

#pragma unroll
    for (int mi = 0; mi < 4; ++mi)
#pragma unroll
        for (int ni = 0; ni < 4; ++ni)
#pragma unroll
            for (int r = 0; r < 4; ++r) {
                float v = acc[mi][ni][r];
                v = (v >= 0.f) ? v : 0.01f * v;
                H[(m0 + mi * 16 + g * 4 + r) * CMID + wave * 64 + ni * 16 + cl] = f2bf(v);
            }
}

// ---------------- K2: conv2 fused with row L2-norm (fragment-layout output) ---------
// Element (row, kcol) stored at
//   (row>>4)*4096 + (kcol>>5)*512 + ((kcol>>3)&3)*128 + (row&15)*8 + (kcol&7)
__global__ __launch_bounds__(512) void conv2_norm(const ushort* __restrict__ H,
                                                  const ushort* __restrict__ W2b,
                                                  ushort* __restrict__ QK) {
    __shared__ ushort As[128 * 32];   // 8 KB
    __shared__ ushort Bs[256 * 32];   // 16 KB
    __shared__ float red[4][128];     // 2 KB
    int tid = threadIdx.x;
    int lane = tid & 63, wave = tid >> 6;
    int wm = wave >> 2, wn = wave & 3;
    int g = lane >> 4, cl = lane & 15;
    int bx = blockIdx.x;
    int half = bx >> 7;
    int u = bx & 127;
    int pb = u & 7, pj = u >> 3;          // pj in [0,16)
    size_t m0 = ((size_t)half * 128 + (size_t)pb * 16 + pj) * 128;

    f32x4 acc[4][4];
#pragma unroll
    for (int i = 0; i < 4; ++i)
#pragma unroll
        for (int j = 0; j < 4; ++j) acc[i][j] = (f32x4)0.f;

    for (int k0 = 0; k0 < CMID; k0 += 32) {
        gload_lds16(H + (m0 + (tid >> 2)) * CMID + k0 + (tid & 3) * 8, As + tid * 8);
#pragma unroll
        for (int si = 0; si < 2; ++si) {
            int s = tid + si * 512;
            gload_lds16(W2b + (size_t)(s >> 2) * CMID + k0 + (s & 3) * 8, Bs + s * 8);
        }
        __syncthreads();
        short8 af[4], bfr[4];
#pragma unroll
        for (int mi = 0; mi < 4; ++mi)
            af[mi] = *(const short8*)&As[(wm * 64 + mi * 16 + cl) * 32 + g * 8];
#pragma unroll
        for (int ni = 0; ni < 4; ++ni)
            bfr[ni] = *(const short8*)&Bs[(wn * 64 + ni * 16 + cl) * 32 + g * 8];
#pragma unroll
        for (int mi = 0; mi < 4; ++mi)
#pragma unroll
            for (int ni = 0; ni < 4; ++ni)
                acc[mi][ni] = __builtin_amdgcn_mfma_f32_16x16x32_bf16(af[mi], bfr[ni], acc[mi][ni], 0, 0, 0);
        __syncthreads();
    }

#pragma unroll
    for (int mi = 0; mi < 4; ++mi)
#pragma unroll
        for (int r = 0; r < 4; ++r) {
            float s = 0.f;
#pragma unroll
            for (int ni = 0; ni < 4; ++ni) { float v = acc[mi][ni][r]; s += v * v; }
#pragma unroll
            for (int off = 1; off < 16; off <<= 1) s += __shfl_xor(s, off, 64);
            if (cl == 0) red[wn][wm * 64 + mi * 16 + g * 4 + r] = s;
        }
    __syncthreads();
#pragma unroll
    for (int mi = 0; mi < 4; ++mi)
#pragma unroll
        for (int r = 0; r < 4; ++r) {
            int row = wm * 64 + mi * 16 + g * 4 + r;
            size_t row_g = m0 + row;
            float tot = red[0][row] + red[1][row] + red[2][row] + red[3][row];
            float inv = 1.0f / fmaxf(sqrtf(tot), NORM_EPS_);
            size_t pbase = (row_g >> 4) * 4096 + (size_t)(row_g & 15) * 8;
#pragma unroll
            for (int ni = 0; ni < 4; ++ni) {
                int kcol = wn * 64 + ni * 16 + cl;
                size_t off = pbase + (size_t)(kcol >> 5) * 512
                           + (size_t)((kcol >> 3) & 3) * 128 + (kcol & 7);
                QK[off] = f2bf(acc[mi][ni][r] * inv);
            }
        }
}

// ---------------- K3: fused scores + softmax(fixed max) + threshold -----------------
// R12 structure; output stores are CACHED (not nontemporal): they land in L2 and
// write back to HBM lazily, overlapping the next block's compute phase on the
// same CU (the nontemporal drain before s_endpgm serialized ~21 us per round).
#define ESTRIDE 2052
__global__ __launch_bounds__(512, 2) void scores_softmax(const ushort* __restrict__ QK,
                                                         float* __restrict__ out) {
    __shared__ ushort eLDS[32 * ESTRIDE];   // 131328 B
    __shared__ float red[8][32];            // 1 KB
    int bid = blockIdx.x;
    int b = bid & 7;                 // batch-per-XCD swizzle
    int m0 = (bid >> 3) * 32;
    int tid = threadIdx.x;
    int lane = tid & 63, wave = tid >> 6;
    int g = lane >> 4, cl = lane & 15;

    const ushort* Qf = QK + ((size_t)(b * N_ + m0) >> 4) * 4096;
    const ushort* Kf = QK + ((size_t)(16384 + b * N_ + wave * 256) >> 4) * 4096;

    short8 af0[8], af1[8];
#pragma unroll
    for (int ks = 0; ks < 8; ++ks) {
        af0[ks] = *(const short8*)(Qf + ks * 512 + lane * 8);
        af1[ks] = *(const short8*)(Qf + 4096 + ks * 512 + lane * 8);
    }

    float rs0[4] = {0.f, 0.f, 0.f, 0.f}, rs1[4] = {0.f, 0.f, 0.f, 0.f};
    int ecol = wave * 256 + cl;

    short8 bfr[2][8];
#pragma unroll
    for (int ks = 0; ks < 8; ++ks)
        bfr[0][ks] = *(const short8*)(Kf + ks * 512 + lane * 8);

#pragma unroll
    for (int ct = 0; ct < 16; ++ct) {
        const int cur = ct & 1, nxt = cur ^ 1;
        if (ct < 15) {
#pragma unroll
            for (int ks = 0; ks < 8; ++ks)
                bfr[nxt][ks] = *(const short8*)(Kf + (size_t)(ct + 1) * 4096 + ks * 512 + lane * 8);
        }
        f32x4 a0 = (f32x4)0.f, a1 = (f32x4)0.f;
#pragma unroll
        for (int ks = 0; ks < 8; ++ks) {
            a0 = __builtin_amdgcn_mfma_f32_16x16x32_bf16(af0[ks], bfr[cur][ks], a0, 0, 0, 0);
            a1 = __builtin_amdgcn_mfma_f32_16x16x32_bf16(af1[ks], bfr[cur][ks], a1, 0, 0, 0);
        }
#pragma unroll
        for (int r = 0; r < 4; ++r) {
            float e0 = __expf((a0[r] - 1.0f) * SCALE_);
            rs0[r] += e0;
            eLDS[(g * 4 + r) * ESTRIDE + ecol + ct * 16] = f2bf(e0);
            float e1 = __expf((a1[r] - 1.0f) * SCALE_);
            rs1[r] += e1;
            eLDS[(16 + g * 4 + r) * ESTRIDE + ecol + ct * 16] = f2bf(e1);
        }
    }

    // row sums: reduce over 16 cl lanes, then across 8 waves via LDS
#pragma unroll
    for (int r = 0; r < 4; ++r) {
        float s = rs0[r];
#pragma unroll
        for (int off = 1; off < 16; off <<= 1) s += __shfl_xor(s, off, 64);
        if (cl == 0) red[wave][g * 4 + r] = s;
        float s1 = rs1[r];
#pragma unroll
        for (int off = 1; off < 16; off <<= 1) s1 += __shfl_xor(s1, off, 64);
        if (cl == 0) red[wave][16 + g * 4 + r] = s1;
    }
    __syncthreads();

    // phase 2: wave w -> rows 4w..4w+3; scale, threshold, store (cached)
    float inv_[4];
#pragma unroll
    for (int rr = 0; rr < 4; ++rr) {
        int row = wave * 4 + rr;
        float t = 0.f;
#pragma unroll
        for (int w = 0; w < 8; ++w) t += red[w][row];
        inv_[rr] = 1.0f / t;
    }

    float* ob = out + (size_t)b * N_ * N_ + (size_t)m0 * N_;
#pragma unroll
    for (int rr = 0; rr < 4; ++rr) {
        int row = wave * 4 + rr;
        const ushort* ep = &eLDS[row * ESTRIDE];
        float* orow = ob + (size_t)row * N_;
#pragma unroll
        for (int j = 0; j < 8; ++j) {
            int c = j * 256 + lane * 4;
            ushort4 ev = *(const ushort4*)&ep[c];
            f32x4 w;
            float t;
            t = bf2f(ev.x) * inv_[rr]; w.x = (t > EPS_THR) ? t : 0.f;
            t = bf2f(ev.y) * inv_[rr]; w.y = (t > EPS_THR) ? t : 0.f;
            t = bf2f(ev.z) * inv_[rr]; w.z = (t > EPS_THR) ? t : 0.f;
            t = bf2f(ev.w) * inv_[rr]; w.w = (t > EPS_THR) ? t : 0.f;
            *(f32x4*)&orow[c] = w;     // cached store: L2 absorbs, lazy writeback
        }
    }
}

extern "C" void kernel_launch(void* const* d_in, const int* in_sizes, int n_in,
                              void* d_out, int out_size, void* d_ws, size_t ws_size,
                              hipStream_t stream) {
    const float* q  = (const float*)d_in[0];
    const float* k  = (const float*)d_in[1];
    const float* W1 = (const float*)d_in[2];
    const float* W2 = (const float*)d_in[3];
    float* out = (float*)d_out;

    // ws: W1b | W2b | QK  (17.3 MB)
    ushort* W1b = (ushort*)d_ws;
    ushort* W2b = W1b + 131072;
    ushort* QK  = W2b + 131072;                 // [2048 panels][4096] bf16 (fragment layout)

    // H scratch inside d_out (overwritten by scores_softmax later)
    ushort* H = (ushort*)d_out;                 // [32768][512] bf16, 33.5 MB
    float* tail = out + (size_t)B_ * N_ * N_;   // key copy destination

    prep_w<<<512, 256, 0, stream>>>(W1, W2, W1b, W2b);
    conv1_fused<<<512, 512, 0, stream>>>(q, k, W1b, H, tail);
    conv2_norm<<<256, 512, 0, stream>>>(H, W2b, QK);
    scores_softmax<<<512, 512, 0, stream>>>(QK, out);
}